// Round 1
// baseline (8784.229 us; speedup 1.0000x reference)
//
#include <hip/hip_runtime.h>
#include <hip/hip_bf16.h>

// Problem constants (from reference)
#define B_TOT 16384
#define DD    384
#define HH    1024
#define DRR   512
#define DMM   1152
#define SS    6     // 1 + KP + KN
#define KPP   3
#define KNN   2

// ---------------------------------------------------------------- helpers
__device__ __forceinline__ float gelu_f(float x) {
    // jax.nn.gelu default (approximate=True, tanh form)
    float x3 = x * x * x;
    return 0.5f * x * (1.0f + tanhf(0.7978845608028654f * (x + 0.044715f * x3)));
}
__device__ __forceinline__ float sigmoid_f(float x) {
    return 1.0f / (1.0f + expf(-x));
}
__device__ __forceinline__ float wave_red_sum(float v) {
    #pragma unroll
    for (int off = 32; off; off >>= 1) v += __shfl_xor(v, off);
    return v;
}

// ---------------------------------------------------------------- GEMM
// C[M,N] = epi( A[M,K] @ W1[K,N] + bias , ... )   (row-major everywhere)
// EPI: 0 none, 1 relu, 2 sigmoid, 3 gelu, 4 (v - A2[r,c]), 5 gelu(vA)*vB (DUAL)
// ACCUM: C += v instead of C = v
// Tile 64x64x16, 256 threads, 4x4 microtile per thread.
template<int EPI, bool ACCUM, bool DUAL>
__global__ __launch_bounds__(256)
void gemm_k(const float* __restrict__ A, const float* __restrict__ W1,
            const float* __restrict__ W2, const float* __restrict__ bias,
            const float* __restrict__ A2, float* __restrict__ C,
            int M, int N, int K)
{
    __shared__ float As[16][68];               // [k][m], +4 pad keeps float4 align
    __shared__ float Bs1[16][68];              // [k][n]
    __shared__ float Bs2[DUAL ? 16 : 1][68];

    const int tid  = threadIdx.x;
    const int tx   = tid & 15, ty = tid >> 4;
    const int row0 = blockIdx.y * 64, col0 = blockIdx.x * 64;

    const int arow = tid >> 2;          // 0..63
    const int acol = (tid & 3) << 2;    // 0,4,8,12
    const int wrow = tid >> 4;          // 0..15
    const int wcol = (tid & 15) << 2;   // 0..60

    const float* Ap  = A  + (size_t)(row0 + arow) * K + acol;
    const float* W1p = W1 + (size_t)wrow * N + col0 + wcol;
    const float* W2p = DUAL ? (W2 + (size_t)wrow * N + col0 + wcol) : W1;

    float acc [4][4] = {};
    float accB[4][4] = {};

    for (int k0 = 0; k0 < K; k0 += 16) {
        float4 av = *(const float4*)(Ap  + k0);
        float4 w1 = *(const float4*)(W1p + (size_t)k0 * N);
        float4 w2;
        if (DUAL) w2 = *(const float4*)(W2p + (size_t)k0 * N);
        As[acol + 0][arow] = av.x;
        As[acol + 1][arow] = av.y;
        As[acol + 2][arow] = av.z;
        As[acol + 3][arow] = av.w;
        *(float4*)&Bs1[wrow][wcol] = w1;
        if (DUAL) *(float4*)&Bs2[wrow][wcol] = w2;
        __syncthreads();
        #pragma unroll
        for (int kk = 0; kk < 16; ++kk) {
            float4 a4 = *(const float4*)&As [kk][ty << 2];
            float4 b4 = *(const float4*)&Bs1[kk][tx << 2];
            float avv[4] = {a4.x, a4.y, a4.z, a4.w};
            float bvv[4] = {b4.x, b4.y, b4.z, b4.w};
            float b2v[4];
            if (DUAL) {
                float4 t = *(const float4*)&Bs2[kk][tx << 2];
                b2v[0] = t.x; b2v[1] = t.y; b2v[2] = t.z; b2v[3] = t.w;
            }
            #pragma unroll
            for (int i = 0; i < 4; ++i)
                #pragma unroll
                for (int j = 0; j < 4; ++j) {
                    acc[i][j] = fmaf(avv[i], bvv[j], acc[i][j]);
                    if (DUAL) accB[i][j] = fmaf(avv[i], b2v[j], accB[i][j]);
                }
        }
        __syncthreads();
    }

    #pragma unroll
    for (int i = 0; i < 4; ++i) {
        int r = row0 + (ty << 2) + i;
        float* Cr = C + (size_t)r * N + col0 + (tx << 2);
        float vb[4];
        #pragma unroll
        for (int j = 0; j < 4; ++j) {
            int c = col0 + (tx << 2) + j;
            float v = acc[i][j];
            if (bias) v += bias[c];
            if      (EPI == 1) v = fmaxf(v, 0.f);
            else if (EPI == 2) v = sigmoid_f(v);
            else if (EPI == 3) v = gelu_f(v);
            else if (EPI == 4) v = v - A2[(size_t)r * N + c];
            else if (EPI == 5) v = gelu_f(v) * accB[i][j];
            vb[j] = v;
        }
        float4 sv = make_float4(vb[0], vb[1], vb[2], vb[3]);
        if (ACCUM) {
            float4 old = *(float4*)Cr;
            sv.x += old.x; sv.y += old.y; sv.z += old.z; sv.w += old.w;
        }
        *(float4*)Cr = sv;
    }
}

// ---------------------------------------------------------------- small kernels

// negm[(b*2+j), d] = head[3+j, b0+b, d] + pred[3+j, b0+b, d]
__global__ void negm_k(const float* __restrict__ head, const float* __restrict__ pred,
                       float* __restrict__ negm, int b0)
{
    int idx = blockIdx.x * 256 + threadIdx.x;       // < Bc*2*384
    int d = idx % DD, rest = idx / DD;
    int j = rest & 1, b = rest >> 1;
    size_t off = ((size_t)(KPP + j) * B_TOT + (b0 + b)) * DD + d;
    negm[idx] = head[off] + pred[off];
}

// Per-b: grouped softmax attention weights + assemble x[b, 0..5, :]
__global__ void asm_k(const float* __restrict__ init_f,
                      const float* __restrict__ head, const float* __restrict__ pred,
                      const float* __restrict__ w_ap, const float* __restrict__ b_ap,
                      const float* __restrict__ w_an, const float* __restrict__ b_an,
                      const float* __restrict__ nf, float* __restrict__ x, int b0)
{
    int lb = blockIdx.x, gb = b0 + lb, lane = threadIdx.x;
    float lp[3], ln2[2];
    #pragma unroll
    for (int j = 0; j < 3; ++j) {
        float p = 0.f;
        for (int d = lane; d < DD; d += 64) {
            size_t off = ((size_t)j * B_TOT + gb) * DD + d;
            p += (head[off] + pred[off]) * w_ap[d];
        }
        lp[j] = wave_red_sum(p) + b_ap[0];
    }
    #pragma unroll
    for (int j = 0; j < 2; ++j) {
        float p = 0.f;
        for (int d = lane; d < DD; d += 64)
            p += nf[((size_t)lb * 2 + j) * DD + d] * w_an[d];
        ln2[j] = wave_red_sum(p) + b_an[0];
    }
    float mp = fmaxf(lp[0], fmaxf(lp[1], lp[2]));
    float e0 = expf(lp[0] - mp), e1 = expf(lp[1] - mp), e2 = expf(lp[2] - mp);
    float sp = e0 + e1 + e2;
    float awp[3] = {e0 / sp, e1 / sp, e2 / sp};
    float mn = fmaxf(ln2[0], ln2[1]);
    float f0 = expf(ln2[0] - mn), f1 = expf(ln2[1] - mn);
    float sn = f0 + f1;
    float awn[2] = {f0 / sn, f1 / sn};

    float* xr = x + (size_t)lb * SS * DD;
    for (int d = lane; d < DD; d += 64) {
        xr[d] = init_f[(size_t)gb * DD + d];
        #pragma unroll
        for (int j = 0; j < 3; ++j) {
            size_t off = ((size_t)j * B_TOT + gb) * DD + d;
            xr[(1 + j) * DD + d] = (head[off] + pred[off]) * awp[j];
        }
        #pragma unroll
        for (int j = 0; j < 2; ++j)
            xr[(4 + j) * DD + d] = nf[((size_t)lb * 2 + j) * DD + d] * awn[j];
    }
}

// rmsnorm per row of [Mrows, 384]; one wave per row, 4 rows per block
__global__ void rms_k(const float* __restrict__ x, const float* __restrict__ g,
                      float* __restrict__ h)
{
    int row  = blockIdx.x * 4 + (threadIdx.x >> 6);
    int lane = threadIdx.x & 63;
    const float* xr = x + (size_t)row * DD;
    float ss = 0.f;
    for (int d = lane; d < DD; d += 64) { float v = xr[d]; ss += v * v; }
    ss = wave_red_sum(ss);
    float sc = rsqrtf(ss / (float)DD + 1e-6f);
    float* hr = h + (size_t)row * DD;
    for (int d = lane; d < DD; d += 64) hr[d] = xr[d] * g[d] * sc;
}

// RG-LRU recurrence over S=6 steps; r,i pre-sigmoided; g pre-gelu'd.
// Writes y*gate into g.
__global__ void rec_k(const float* __restrict__ u, const float* __restrict__ r,
                      const float* __restrict__ i_, float* __restrict__ g,
                      const float* __restrict__ lam, int Bc)
{
    int idx = blockIdx.x * 256 + threadIdx.x;       // < Bc*512
    int d = idx & (DRR - 1), b = idx >> 9;
    float a_base = -8.0f * log1pf(expf(lam[d]));    // -RG_C * softplus(lam)
    float h = 0.f;
    size_t base = (size_t)b * SS * DRR + d;
    #pragma unroll
    for (int t = 0; t < SS; ++t) {
        size_t off = base + (size_t)t * DRR;
        float rr = r[off], ii = i_[off], uu = u[off];
        float e = expf(a_base * rr);
        h = e * h + sqrtf(fmaxf(0.f, 1.f - e * e)) * (ii * uu);
        g[off] = h * g[off];
    }
}

// wproj[d] = sum_k fa_wo[d,k] * fa_wl[k]   (collapses fa_out GEMM into a GEMV)
__global__ void wproj_k(const float* __restrict__ fa_wo, const float* __restrict__ fa_wl,
                        float* __restrict__ wproj)
{
    int d = threadIdx.x;  // 384 threads
    float s = 0.f;
    for (int k = 0; k < DD; ++k) s += fa_wo[(size_t)d * DD + k] * fa_wl[k];
    wproj[d] = s;
}

// Final: logits = Afa @ wproj (+bl), softmax over S, out = (1/6) sum_t x_t * w_t
__global__ void final_k(const float* __restrict__ x, const float* __restrict__ Afa,
                        const float* __restrict__ wproj, const float* __restrict__ fa_bl,
                        float* __restrict__ out, int b0)
{
    int lb = blockIdx.x, gb = b0 + lb, lane = threadIdx.x;
    float lg[SS];
    #pragma unroll
    for (int t = 0; t < SS; ++t) {
        float p = 0.f;
        const float* ar = Afa + ((size_t)lb * SS + t) * DD;
        for (int d = lane; d < DD; d += 64) p += ar[d] * wproj[d];
        lg[t] = wave_red_sum(p) + fa_bl[0];
    }
    float m = lg[0];
    #pragma unroll
    for (int t = 1; t < SS; ++t) m = fmaxf(m, lg[t]);
    float e[SS], s = 0.f;
    #pragma unroll
    for (int t = 0; t < SS; ++t) { e[t] = expf(lg[t] - m); s += e[t]; }
    float inv = 1.0f / s;
    const float* xr = x + (size_t)lb * SS * DD;
    for (int d = lane; d < DD; d += 64) {
        float acc = 0.f;
        #pragma unroll
        for (int t = 0; t < SS; ++t) acc += xr[t * DD + d] * (e[t] * inv);
        out[(size_t)gb * DD + d] = acc * (1.0f / 6.0f);
    }
}

// ---------------------------------------------------------------- launch
extern "C" void kernel_launch(void* const* d_in, const int* in_sizes, int n_in,
                              void* d_out, int out_size, void* d_ws, size_t ws_size,
                              hipStream_t stream)
{
    (void)in_sizes; (void)n_in; (void)out_size;
    const float* init_f  = (const float*)d_in[0];
    const float* head    = (const float*)d_in[1];
    const float* pred    = (const float*)d_in[2];
    const float* w_ap    = (const float*)d_in[3];
    const float* b_ap    = (const float*)d_in[4];
    const float* w_an    = (const float*)d_in[5];
    const float* b_an    = (const float*)d_in[6];
    const float* nt_w1   = (const float*)d_in[7];
    const float* nt_b1   = (const float*)d_in[8];
    const float* nt_w2   = (const float*)d_in[9];
    const float* nt_b2   = (const float*)d_in[10];
    const float* g1      = (const float*)d_in[11];
    const float* rg_wx   = (const float*)d_in[12];
    const float* rg_bx   = (const float*)d_in[13];
    const float* rg_wy   = (const float*)d_in[14];
    const float* rg_by   = (const float*)d_in[15];
    const float* rg_wr   = (const float*)d_in[16];
    const float* rg_br   = (const float*)d_in[17];
    const float* rg_wi   = (const float*)d_in[18];
    const float* rg_bi   = (const float*)d_in[19];
    const float* rg_lam  = (const float*)d_in[20];
    const float* rg_wo   = (const float*)d_in[21];
    const float* rg_bo   = (const float*)d_in[22];
    const float* g2      = (const float*)d_in[23];
    const float* mlp_wg  = (const float*)d_in[24];
    const float* mlp_wv  = (const float*)d_in[25];
    const float* mlp_wo  = (const float*)d_in[26];
    const float* fa_wg   = (const float*)d_in[27];
    const float* fa_wv   = (const float*)d_in[28];
    const float* fa_wo   = (const float*)d_in[29];
    const float* fa_wl   = (const float*)d_in[30];
    const float* fa_bl   = (const float*)d_in[31];
    float* out = (float*)d_out;

    float* ws_f  = (float*)d_ws;
    float* wproj = ws_f;                       // 512 floats reserved
    wproj_k<<<1, DD, 0, stream>>>(fa_wo, fa_wl, wproj);

    // Pick chunk size to fit workspace: per-chunk floats = 2304+2304+12288 = 16896 per b
    int Bc = B_TOT;
    while (Bc > 32 && 2048 + (size_t)16896 * 4 * Bc > ws_size) Bc >>= 1;

    for (int b0 = 0; b0 < B_TOT; b0 += Bc) {
        const int M  = Bc * SS;    // token rows
        const int M2 = Bc * KNN;   // neg rows
        float* xbuf = ws_f + 512;
        float* hbuf = xbuf + (size_t)2304 * Bc;
        float* big  = hbuf + (size_t)2304 * Bc;   // 12288*Bc floats
        // stage-1 layout in big
        float* negm   = big;                       //  768*Bc
        float* hidden = big + (size_t)768  * Bc;   // 2048*Bc
        float* nf     = big + (size_t)2816 * Bc;   //  768*Bc
        // rg layout in big
        float* ubuf = big;                         // 3072*Bc each
        float* gbuf = big + (size_t)3072 * Bc;
        float* rbuf = big + (size_t)6144 * Bc;
        float* ibuf = big + (size_t)9216 * Bc;
        float* Tbuf = big;                         // 6912*Bc (mlp)
        float* Afa  = big;                         // 2304*Bc (final attn)

        // ---- stage 1: neg-MLP + grouped attention + assemble x [Bc,6,384]
        negm_k<<<Bc * 3, 256, 0, stream>>>(head, pred, negm, b0);
        gemm_k<1, false, false><<<dim3(HH / 64, M2 / 64), 256, 0, stream>>>(
            negm, nt_w1, nullptr, nt_b1, nullptr, hidden, M2, HH, DD);
        gemm_k<4, false, false><<<dim3(DD / 64, M2 / 64), 256, 0, stream>>>(
            hidden, nt_w2, nullptr, nt_b2, negm, nf, M2, DD, HH);
        asm_k<<<Bc, 64, 0, stream>>>(init_f, head, pred, w_ap, b_ap, w_an, b_an,
                                     nf, xbuf, b0);

        // ---- Griffin recurrent branch
        rms_k<<<M / 4, 256, 0, stream>>>(xbuf, g1, hbuf);
        gemm_k<0, false, false><<<dim3(DRR / 64, M / 64), 256, 0, stream>>>(
            hbuf, rg_wx, nullptr, rg_bx, nullptr, ubuf, M, DRR, DD);
        gemm_k<3, false, false><<<dim3(DRR / 64, M / 64), 256, 0, stream>>>(
            hbuf, rg_wy, nullptr, rg_by, nullptr, gbuf, M, DRR, DD);
        gemm_k<2, false, false><<<dim3(DRR / 64, M / 64), 256, 0, stream>>>(
            ubuf, rg_wr, nullptr, rg_br, nullptr, rbuf, M, DRR, DRR);
        gemm_k<2, false, false><<<dim3(DRR / 64, M / 64), 256, 0, stream>>>(
            ubuf, rg_wi, nullptr, rg_bi, nullptr, ibuf, M, DRR, DRR);
        rec_k<<<Bc * 2, 256, 0, stream>>>(ubuf, rbuf, ibuf, gbuf, rg_lam, Bc);
        gemm_k<0, true, false><<<dim3(DD / 64, M / 64), 256, 0, stream>>>(
            gbuf, rg_wo, nullptr, rg_bo, nullptr, xbuf, M, DD, DRR);

        // ---- gated-MLP residual branch
        rms_k<<<M / 4, 256, 0, stream>>>(xbuf, g2, hbuf);
        gemm_k<5, false, true><<<dim3(DMM / 64, M / 64), 256, 0, stream>>>(
            hbuf, mlp_wg, mlp_wv, nullptr, nullptr, Tbuf, M, DMM, DD);
        gemm_k<0, true, false><<<dim3(DD / 64, M / 64), 256, 0, stream>>>(
            Tbuf, mlp_wo, nullptr, nullptr, nullptr, xbuf, M, DD, DMM);

        // ---- final attention aggregation
        gemm_k<5, false, true><<<dim3(DD / 64, M / 64), 256, 0, stream>>>(
            xbuf, fa_wg, fa_wv, nullptr, nullptr, Afa, M, DD, DD);
        final_k<<<Bc, 64, 0, stream>>>(xbuf, Afa, wproj, fa_bl, out, b0);
    }
}

// Round 2
// 5550.229 us; speedup vs baseline: 1.5827x; 1.5827x over previous
//
#include <hip/hip_runtime.h>
#include <hip/hip_bf16.h>

// Problem constants (from reference)
#define B_TOT 16384
#define DD    384
#define HH    1024
#define DRR   512
#define DMM   1152
#define SS    6     // 1 + KP + KN
#define KPP   3
#define KNN   2

typedef unsigned short ushort_t;
typedef __bf16 bf16x8 __attribute__((ext_vector_type(8)));
typedef float  f32x4  __attribute__((ext_vector_type(4)));

// ---------------------------------------------------------------- helpers
__device__ __forceinline__ float gelu_f(float x) {
    float x3 = x * x * x;
    return 0.5f * x * (1.0f + tanhf(0.7978845608028654f * (x + 0.044715f * x3)));
}
__device__ __forceinline__ float sigmoid_f(float x) {
    return 1.0f / (1.0f + expf(-x));
}
__device__ __forceinline__ float wave_red_sum(float v) {
    #pragma unroll
    for (int off = 32; off; off >>= 1) v += __shfl_xor(v, off);
    return v;
}
__device__ __forceinline__ ushort_t f2bf(float v) {
    __hip_bfloat16 h = __float2bfloat16(v);
    return *reinterpret_cast<ushort_t*>(&h);
}

// ---------------------------------------------------------------- MFMA GEMM
// C[M,N] = epi( A[M,K](bf16) @ WT[N,K](bf16)^T + bias )
// EPI: 0 none, 1 relu, 2 sigmoid, 3 gelu, 4 v - X2[r,c], 6 gelu(X2[r,c]) * v
// ACCUM: v += C_old.  C (fp32) and Ch (bf16) each optional (nullptr -> skip).
// Tile 128x128, BK=64, 4 waves (2x2), each wave 64x64 via 4x4 frags of 16x16x32.
#define ROWE 72   // padded LDS row: 72 bf16 = 144 B (16B-aligned, conflict-free frags)

template<int EPI, bool ACCUM>
__global__ __launch_bounds__(256, 2)
void bgemm(const ushort_t* __restrict__ A, const ushort_t* __restrict__ WT,
           const float* __restrict__ bias, const float* __restrict__ X2,
           float* __restrict__ C, ushort_t* __restrict__ Ch,
           int M, int N, int K)
{
    __shared__ ushort_t sm[2][128 * ROWE];   // [0]=A tile, [1]=B tile (36 KiB)

    const int tid = threadIdx.x;
    const int l   = tid & 63;
    const int w   = tid >> 6;
    const int wr  = w >> 1, wc = w & 1;
    const int row0 = blockIdx.y * 128, col0 = blockIdx.x * 128;

    // staging: thread covers 32 k-elems of one row of each tile
    const int sr   = tid & 127;
    const int sseg = tid >> 7;                 // 0/1 -> k-offset 0/32
    const ushort_t* Ag = A  + (size_t)(row0 + sr) * K + sseg * 32;
    const ushort_t* Bg = WT + (size_t)(col0 + sr) * K + sseg * 32;
    const int swb = sr * ROWE + sseg * 32;     // elem offset in LDS

    const int lr = l & 15;       // frag row/col within 16
    const int hi = l >> 4;       // k sub-group

    f32x4 acc[4][4] = {};
    uint4 ra[4], rb[4];

    const int NT = K >> 6;       // K / 64

    // prologue: tile 0
    {
        const uint4* sa = (const uint4*)Ag;
        const uint4* sb = (const uint4*)Bg;
        ra[0]=sa[0]; ra[1]=sa[1]; ra[2]=sa[2]; ra[3]=sa[3];
        rb[0]=sb[0]; rb[1]=sb[1]; rb[2]=sb[2]; rb[3]=sb[3];
        uint4* dA = (uint4*)&sm[0][swb];
        uint4* dB = (uint4*)&sm[1][swb];
        dA[0]=ra[0]; dA[1]=ra[1]; dA[2]=ra[2]; dA[3]=ra[3];
        dB[0]=rb[0]; dB[1]=rb[1]; dB[2]=rb[2]; dB[3]=rb[3];
    }
    __syncthreads();

    for (int t = 0; t < NT; ++t) {
        if (t + 1 < NT) {   // issue next tile's global loads early (hide under MFMA)
            const uint4* sa = (const uint4*)(Ag + (size_t)(t + 1) * 64);
            const uint4* sb = (const uint4*)(Bg + (size_t)(t + 1) * 64);
            ra[0]=sa[0]; ra[1]=sa[1]; ra[2]=sa[2]; ra[3]=sa[3];
            rb[0]=sb[0]; rb[1]=sb[1]; rb[2]=sb[2]; rb[3]=sb[3];
        }
        #pragma unroll
        for (int ks = 0; ks < 2; ++ks) {
            bf16x8 af[4], bfr[4];
            #pragma unroll
            for (int m = 0; m < 4; ++m)
                af[m] = *(const bf16x8*)&sm[0][(wr*64 + m*16 + lr) * ROWE + ks*32 + hi*8];
            #pragma unroll
            for (int n = 0; n < 4; ++n)
                bfr[n] = *(const bf16x8*)&sm[1][(wc*64 + n*16 + lr) * ROWE + ks*32 + hi*8];
            #pragma unroll
            for (int m = 0; m < 4; ++m)
                #pragma unroll
                for (int n = 0; n < 4; ++n)
                    acc[m][n] = __builtin_amdgcn_mfma_f32_16x16x32_bf16(
                        af[m], bfr[n], acc[m][n], 0, 0, 0);
        }
        __syncthreads();
        if (t + 1 < NT) {
            uint4* dA = (uint4*)&sm[0][swb];
            uint4* dB = (uint4*)&sm[1][swb];
            dA[0]=ra[0]; dA[1]=ra[1]; dA[2]=ra[2]; dA[3]=ra[3];
            dB[0]=rb[0]; dB[1]=rb[1]; dB[2]=rb[2]; dB[3]=rb[3];
            __syncthreads();
        }
    }

    // epilogue: C/D frag mapping col = l&15, row = (l>>4)*4 + j   [m89-verified]
    #pragma unroll
    for (int m = 0; m < 4; ++m) {
        #pragma unroll
        for (int n = 0; n < 4; ++n) {
            const int r0 = row0 + wr*64 + m*16 + hi*4;
            const int c  = col0 + wc*64 + n*16 + lr;
            const float bv = bias ? bias[c] : 0.f;
            #pragma unroll
            for (int j = 0; j < 4; ++j) {
                const int r = r0 + j;
                float v = acc[m][n][j] + bv;
                if      (EPI == 1) v = fmaxf(v, 0.f);
                else if (EPI == 2) v = sigmoid_f(v);
                else if (EPI == 3) v = gelu_f(v);
                else if (EPI == 4) v = v - X2[(size_t)r * N + c];
                else if (EPI == 6) v = gelu_f(X2[(size_t)r * N + c]) * v;
                if (ACCUM) v += C[(size_t)r * N + c];
                if (C)  C [(size_t)r * N + c] = v;
                if (Ch) Ch[(size_t)r * N + c] = f2bf(v);
            }
        }
    }
}

// ---------------------------------------------------------------- small kernels

// transpose+convert weight: WT[n*K+k] = bf16(W[k*N+n])
__global__ void tr_k(const float* __restrict__ W, ushort_t* __restrict__ WT,
                     int K, int N)
{
    int idx = blockIdx.x * 256 + threadIdx.x;
    if (idx >= K * N) return;
    int n = idx / K, k = idx % K;
    WT[idx] = f2bf(W[(size_t)k * N + n]);
}

// negm = head+pred (negated atomics), fp32 + bf16 copies
__global__ void negm_k(const float* __restrict__ head, const float* __restrict__ pred,
                       float* __restrict__ negm, ushort_t* __restrict__ negm_h, int b0)
{
    int idx = blockIdx.x * 256 + threadIdx.x;       // < Bc*2*384
    int d = idx % DD, rest = idx / DD;
    int j = rest & 1, b = rest >> 1;
    size_t off = ((size_t)(KPP + j) * B_TOT + (b0 + b)) * DD + d;
    float v = head[off] + pred[off];
    negm[idx] = v;
    negm_h[idx] = f2bf(v);
}

// Per-b: grouped softmax attention weights + assemble x[b, 0..5, :]
__global__ void asm_k(const float* __restrict__ init_f,
                      const float* __restrict__ head, const float* __restrict__ pred,
                      const float* __restrict__ w_ap, const float* __restrict__ b_ap,
                      const float* __restrict__ w_an, const float* __restrict__ b_an,
                      const float* __restrict__ nf, float* __restrict__ x, int b0)
{
    int lb = blockIdx.x, gb = b0 + lb, lane = threadIdx.x;
    float lp[3], ln2[2];
    #pragma unroll
    for (int j = 0; j < 3; ++j) {
        float p = 0.f;
        for (int d = lane; d < DD; d += 64) {
            size_t off = ((size_t)j * B_TOT + gb) * DD + d;
            p += (head[off] + pred[off]) * w_ap[d];
        }
        lp[j] = wave_red_sum(p) + b_ap[0];
    }
    #pragma unroll
    for (int j = 0; j < 2; ++j) {
        float p = 0.f;
        for (int d = lane; d < DD; d += 64)
            p += nf[((size_t)lb * 2 + j) * DD + d] * w_an[d];
        ln2[j] = wave_red_sum(p) + b_an[0];
    }
    float mp = fmaxf(lp[0], fmaxf(lp[1], lp[2]));
    float e0 = expf(lp[0] - mp), e1 = expf(lp[1] - mp), e2 = expf(lp[2] - mp);
    float sp = e0 + e1 + e2;
    float awp[3] = {e0 / sp, e1 / sp, e2 / sp};
    float mn = fmaxf(ln2[0], ln2[1]);
    float f0 = expf(ln2[0] - mn), f1 = expf(ln2[1] - mn);
    float sn = f0 + f1;
    float awn[2] = {f0 / sn, f1 / sn};

    float* xr = x + (size_t)lb * SS * DD;
    for (int d = lane; d < DD; d += 64) {
        xr[d] = init_f[(size_t)gb * DD + d];
        #pragma unroll
        for (int j = 0; j < 3; ++j) {
            size_t off = ((size_t)j * B_TOT + gb) * DD + d;
            xr[(1 + j) * DD + d] = (head[off] + pred[off]) * awp[j];
        }
        #pragma unroll
        for (int j = 0; j < 2; ++j)
            xr[(4 + j) * DD + d] = nf[((size_t)lb * 2 + j) * DD + d] * awn[j];
    }
}

// rmsnorm per row -> bf16 output; one wave per row, 4 rows per block
__global__ void rms_k(const float* __restrict__ x, const float* __restrict__ g,
                      ushort_t* __restrict__ h)
{
    int row  = blockIdx.x * 4 + (threadIdx.x >> 6);
    int lane = threadIdx.x & 63;
    const float* xr = x + (size_t)row * DD;
    float ss = 0.f;
    for (int d = lane; d < DD; d += 64) { float v = xr[d]; ss += v * v; }
    ss = wave_red_sum(ss);
    float sc = rsqrtf(ss / (float)DD + 1e-6f);
    ushort_t* hr = h + (size_t)row * DD;
    for (int d = lane; d < DD; d += 64) hr[d] = f2bf(xr[d] * g[d] * sc);
}

// RG-LRU recurrence; r,i pre-sigmoided; g pre-gelu'd. prod = y * gate (bf16).
__global__ void rec_k(const float* __restrict__ u, const float* __restrict__ r,
                      const float* __restrict__ i_, const float* __restrict__ g,
                      const float* __restrict__ lam, ushort_t* __restrict__ prod)
{
    int idx = blockIdx.x * 256 + threadIdx.x;       // < Bc*512
    int d = idx & (DRR - 1), b = idx >> 9;
    float a_base = -8.0f * log1pf(expf(lam[d]));    // -RG_C * softplus(lam)
    float h = 0.f;
    size_t base = (size_t)b * SS * DRR + d;
    #pragma unroll
    for (int t = 0; t < SS; ++t) {
        size_t off = base + (size_t)t * DRR;
        float rr = r[off], ii = i_[off], uu = u[off];
        float e = expf(a_base * rr);
        h = e * h + sqrtf(fmaxf(0.f, 1.f - e * e)) * (ii * uu);
        prod[off] = f2bf(h * g[off]);
    }
}

// wproj[d] = sum_k fa_wo[d,k] * fa_wl[k]
__global__ void wproj_k(const float* __restrict__ fa_wo, const float* __restrict__ fa_wl,
                        float* __restrict__ wproj)
{
    int d = threadIdx.x;  // 384 threads
    float s = 0.f;
    for (int k = 0; k < DD; ++k) s += fa_wo[(size_t)d * DD + k] * fa_wl[k];
    wproj[d] = s;
}

// Final: logits = Afa @ wproj (+bl), softmax over S, out = (1/6) sum_t x_t * w_t
__global__ void final_k(const float* __restrict__ x, const float* __restrict__ Afa,
                        const float* __restrict__ wproj, const float* __restrict__ fa_bl,
                        float* __restrict__ out, int b0)
{
    int lb = blockIdx.x, gb = b0 + lb, lane = threadIdx.x;
    float lg[SS];
    #pragma unroll
    for (int t = 0; t < SS; ++t) {
        float p = 0.f;
        const float* ar = Afa + ((size_t)lb * SS + t) * DD;
        for (int d = lane; d < DD; d += 64) p += ar[d] * wproj[d];
        lg[t] = wave_red_sum(p) + fa_bl[0];
    }
    float m = lg[0];
    #pragma unroll
    for (int t = 1; t < SS; ++t) m = fmaxf(m, lg[t]);
    float e[SS], s = 0.f;
    #pragma unroll
    for (int t = 0; t < SS; ++t) { e[t] = expf(lg[t] - m); s += e[t]; }
    float inv = 1.0f / s;
    const float* xr = x + (size_t)lb * SS * DD;
    for (int d = lane; d < DD; d += 64) {
        float acc = 0.f;
        #pragma unroll
        for (int t = 0; t < SS; ++t) acc += xr[t * DD + d] * (e[t] * inv);
        out[(size_t)gb * DD + d] = acc * (1.0f / 6.0f);
    }
}

// ---------------------------------------------------------------- launch
extern "C" void kernel_launch(void* const* d_in, const int* in_sizes, int n_in,
                              void* d_out, int out_size, void* d_ws, size_t ws_size,
                              hipStream_t stream)
{
    (void)in_sizes; (void)n_in; (void)out_size;
    const float* init_f  = (const float*)d_in[0];
    const float* head    = (const float*)d_in[1];
    const float* pred    = (const float*)d_in[2];
    const float* w_ap    = (const float*)d_in[3];
    const float* b_ap    = (const float*)d_in[4];
    const float* w_an    = (const float*)d_in[5];
    const float* b_an    = (const float*)d_in[6];
    const float* nt_w1   = (const float*)d_in[7];
    const float* nt_b1   = (const float*)d_in[8];
    const float* nt_w2   = (const float*)d_in[9];
    const float* nt_b2   = (const float*)d_in[10];
    const float* g1      = (const float*)d_in[11];
    const float* rg_wx   = (const float*)d_in[12];
    const float* rg_bx   = (const float*)d_in[13];
    const float* rg_wy   = (const float*)d_in[14];
    const float* rg_by   = (const float*)d_in[15];
    const float* rg_wr   = (const float*)d_in[16];
    const float* rg_br   = (const float*)d_in[17];
    const float* rg_wi   = (const float*)d_in[18];
    const float* rg_bi   = (const float*)d_in[19];
    const float* rg_lam  = (const float*)d_in[20];
    const float* rg_wo   = (const float*)d_in[21];
    const float* rg_bo   = (const float*)d_in[22];
    const float* g2      = (const float*)d_in[23];
    const float* mlp_wg  = (const float*)d_in[24];
    const float* mlp_wv  = (const float*)d_in[25];
    const float* mlp_wo  = (const float*)d_in[26];
    const float* fa_wg   = (const float*)d_in[27];
    const float* fa_wv   = (const float*)d_in[28];
    const float* fa_wo   = (const float*)d_in[29];
    const float* fa_wl   = (const float*)d_in[30];
    const float* fa_bl   = (const float*)d_in[31];
    float* out = (float*)d_out;

    float* ws_f  = (float*)d_ws;
    float* wproj = ws_f;                                   // 512 f32

    // ---- bf16 transposed weights (once per launch)
    ushort_t* wt = (ushort_t*)(ws_f + 512);
    struct WSpec { const float* W; int K, N; };
    const WSpec specs[12] = {
        {nt_w1, DD, HH}, {nt_w2, HH, DD},
        {rg_wx, DD, DRR}, {rg_wy, DD, DRR},
        {rg_wr, DRR, DRR}, {rg_wi, DRR, DRR}, {rg_wo, DRR, DD},
        {mlp_wg, DD, DMM}, {mlp_wv, DD, DMM}, {mlp_wo, DMM, DD},
        {fa_wg, DD, DD}, {fa_wv, DD, DD},
    };
    ushort_t* wtp[12];
    {
        size_t o = 0;
        for (int i = 0; i < 12; ++i) {
            wtp[i] = wt + o;
            size_t e = (size_t)specs[i].K * specs[i].N;
            tr_k<<<(int)((e + 255) / 256), 256, 0, stream>>>(specs[i].W, wtp[i],
                                                             specs[i].K, specs[i].N);
            o += e;
        }
    }
    ushort_t* nt_w1T = wtp[0], *nt_w2T = wtp[1];
    ushort_t* rg_wxT = wtp[2], *rg_wyT = wtp[3], *rg_wrT = wtp[4];
    ushort_t* rg_wiT = wtp[5], *rg_woT = wtp[6];
    ushort_t* mlp_wgT = wtp[7], *mlp_wvT = wtp[8], *mlp_woT = wtp[9];
    ushort_t* fa_wgT = wtp[10], *fa_wvT = wtp[11];

    wproj_k<<<1, DD, 0, stream>>>(fa_wo, fa_wl, wproj);

    // ---- chunked main pipeline
    const size_t fixed_f32 = 512 + 1761280;                // wproj + bf16 weights
    const size_t per_b_f32 = 2304 + 1152 + 16512;          // xbuf + xbuf_h + big
    int Bc = B_TOT;
    while (Bc > 64 && (fixed_f32 + per_b_f32 * (size_t)Bc) * 4 > ws_size) Bc >>= 1;

    float* arena = ws_f + fixed_f32;

    for (int b0 = 0; b0 < B_TOT; b0 += Bc) {
        const int M  = Bc * SS;    // token rows  (multiple of 128 for Bc>=64)
        const int M2 = Bc * KNN;   // neg rows
        float*    xbuf   = arena;
        ushort_t* xbuf_h = (ushort_t*)(arena + (size_t)2304 * Bc);
        float*    big    = arena + (size_t)(2304 + 1152) * Bc;

        // phase-A layout (f32 units from big)
        float*    negm     = big;
        ushort_t* negm_h   = (ushort_t*)(big + (size_t)768  * Bc);
        ushort_t* hidden_h = (ushort_t*)(big + (size_t)1152 * Bc);
        float*    nf       = big + (size_t)2176 * Bc;
        // phase-RG layout
        ushort_t* hbuf_h = (ushort_t*)big;
        float*    ubuf   = big + (size_t)1152  * Bc;
        ushort_t* ubuf_h = (ushort_t*)(big + (size_t)4224 * Bc);
        float*    gbuf   = big + (size_t)5760  * Bc;
        float*    rbuf   = big + (size_t)8832  * Bc;
        float*    ibuf   = big + (size_t)11904 * Bc;
        ushort_t* prod_h = (ushort_t*)(big + (size_t)14976 * Bc);
        // phase-MLP layout
        ushort_t* h2_h   = (ushort_t*)big;
        float*    Gbuf   = big + (size_t)1152 * Bc;
        ushort_t* Tbuf_h = (ushort_t*)(big + (size_t)8064 * Bc);
        // phase-FA layout
        float*    G2buf  = big;
        float*    Afa    = big + (size_t)2304 * Bc;

        // ---- stage 1: neg-MLP + grouped attention + assemble x [Bc,6,384]
        negm_k<<<Bc * 3, 256, 0, stream>>>(head, pred, negm, negm_h, b0);
        bgemm<1, false><<<dim3(HH / 128, M2 / 128), 256, 0, stream>>>(
            negm_h, nt_w1T, nt_b1, nullptr, nullptr, hidden_h, M2, HH, DD);
        bgemm<4, false><<<dim3(DD / 128, M2 / 128), 256, 0, stream>>>(
            hidden_h, nt_w2T, nt_b2, negm, nf, nullptr, M2, DD, HH);
        asm_k<<<Bc, 64, 0, stream>>>(init_f, head, pred, w_ap, b_ap, w_an, b_an,
                                     nf, xbuf, b0);

        // ---- Griffin recurrent branch
        rms_k<<<M / 4, 256, 0, stream>>>(xbuf, g1, hbuf_h);
        bgemm<0, false><<<dim3(DRR / 128, M / 128), 256, 0, stream>>>(
            hbuf_h, rg_wxT, rg_bx, nullptr, ubuf, ubuf_h, M, DRR, DD);
        bgemm<3, false><<<dim3(DRR / 128, M / 128), 256, 0, stream>>>(
            hbuf_h, rg_wyT, rg_by, nullptr, gbuf, nullptr, M, DRR, DD);
        bgemm<2, false><<<dim3(DRR / 128, M / 128), 256, 0, stream>>>(
            ubuf_h, rg_wrT, rg_br, nullptr, rbuf, nullptr, M, DRR, DRR);
        bgemm<2, false><<<dim3(DRR / 128, M / 128), 256, 0, stream>>>(
            ubuf_h, rg_wiT, rg_bi, nullptr, ibuf, nullptr, M, DRR, DRR);
        rec_k<<<Bc * 2, 256, 0, stream>>>(ubuf, rbuf, ibuf, gbuf, rg_lam, prod_h);
        bgemm<0, true><<<dim3(DD / 128, M / 128), 256, 0, stream>>>(
            prod_h, rg_woT, rg_bo, nullptr, xbuf, nullptr, M, DD, DRR);

        // ---- gated-MLP residual branch (split dual: G then gelu(G)*V fused)
        rms_k<<<M / 4, 256, 0, stream>>>(xbuf, g2, h2_h);
        bgemm<0, false><<<dim3(DMM / 128, M / 128), 256, 0, stream>>>(
            h2_h, mlp_wgT, nullptr, nullptr, Gbuf, nullptr, M, DMM, DD);
        bgemm<6, false><<<dim3(DMM / 128, M / 128), 256, 0, stream>>>(
            h2_h, mlp_wvT, nullptr, Gbuf, nullptr, Tbuf_h, M, DMM, DD);
        bgemm<0, true><<<dim3(DD / 128, M / 128), 256, 0, stream>>>(
            Tbuf_h, mlp_woT, nullptr, nullptr, xbuf, xbuf_h, M, DD, DMM);

        // ---- final attention aggregation
        bgemm<0, false><<<dim3(DD / 128, M / 128), 256, 0, stream>>>(
            xbuf_h, fa_wgT, nullptr, nullptr, G2buf, nullptr, M, DD, DD);
        bgemm<6, false><<<dim3(DD / 128, M / 128), 256, 0, stream>>>(
            xbuf_h, fa_wvT, nullptr, G2buf, Afa, nullptr, M, DD, DD);
        final_k<<<Bc, 64, 0, stream>>>(xbuf, Afa, wproj, fa_bl, out, b0);
    }
}

// Round 3
// 4302.071 us; speedup vs baseline: 2.0419x; 1.2901x over previous
//
#include <hip/hip_runtime.h>
#include <hip/hip_bf16.h>

// Problem constants (from reference)
#define B_TOT 16384
#define DD    384
#define HH    1024
#define DRR   512
#define DMM   1152
#define SS    6     // 1 + KP + KN
#define KPP   3
#define KNN   2

typedef unsigned short ushort_t;
typedef __bf16 bf16x8 __attribute__((ext_vector_type(8)));
typedef float  f32x4  __attribute__((ext_vector_type(4)));

#define ROWE 72   // padded LDS row: 72 bf16 = 144 B (16B-aligned, conflict-free frags)

// ---------------------------------------------------------------- helpers
__device__ __forceinline__ float gelu_f(float x) {
    float x3 = x * x * x;
    return 0.5f * x * (1.0f + tanhf(0.7978845608028654f * (x + 0.044715f * x3)));
}
__device__ __forceinline__ float sigmoid_f(float x) {
    return 1.0f / (1.0f + expf(-x));
}
__device__ __forceinline__ float wave_red_sum(float v) {
    #pragma unroll
    for (int off = 32; off; off >>= 1) v += __shfl_xor(v, off);
    return v;
}
__device__ __forceinline__ ushort_t f2bf(float v) {
    __hip_bfloat16 h = __float2bfloat16(v);
    return *reinterpret_cast<ushort_t*>(&h);
}
__device__ __forceinline__ float bf2f(ushort_t u) {
    unsigned int x = ((unsigned int)u) << 16;
    return __uint_as_float(x);
}
// XCD-aware bijective block swizzle: give each XCD a contiguous chunk of the
// linearized grid so consecutive col-blocks (same A-panel) share one L2.
__device__ __forceinline__ void swz_xy(int& bx, int& by) {
    const int nx = gridDim.x;
    const int nwg = nx * gridDim.y;
    const int h = by * nx + bx;
    const int q = nwg >> 3, r = nwg & 7;
    const int xcd = h & 7, lo = h >> 3;
    const int lin = (xcd < r) ? (xcd * (q + 1) + lo)
                              : (r * (q + 1) + (xcd - r) * q + lo);
    bx = lin % nx;
    by = lin / nx;
}

// ---------------------------------------------------------------- MFMA GEMM
// C[M,N] = epi( A[M,K](bf16) @ WT[N,K](bf16)^T + bias )
// EPI: 0 none, 1 relu->Ch, 4 (v - X2bf16)->Ch, 7 split-xy (c<512 -> Ch, else gelu -> Ch2)
// ACCUM: v += C_old. C fp32 / Ch bf16 optional.
template<int EPI, bool ACCUM>
__global__ __launch_bounds__(256, 4)
void bgemm(const ushort_t* __restrict__ A, const ushort_t* __restrict__ WT,
           const float* __restrict__ bias, const ushort_t* __restrict__ X2,
           float* __restrict__ C, ushort_t* __restrict__ Ch, ushort_t* __restrict__ Ch2,
           int M, int N, int K)
{
    __shared__ ushort_t sm[2][128 * ROWE];

    int bx = blockIdx.x, by = blockIdx.y;
    swz_xy(bx, by);
    const int tid = threadIdx.x;
    const int l = tid & 63, w = tid >> 6;
    const int wr = w >> 1, wc = w & 1;
    const int lr = l & 15, hi = l >> 4;
    const int row0 = by * 128, col0 = bx * 128;

    const int sr = tid & 127, sseg = tid >> 7;
    const int swb = sr * ROWE + sseg * 32;
    const ushort_t* Ag = A  + (size_t)(row0 + sr) * K + sseg * 32;
    const ushort_t* Bg = WT + (size_t)(col0 + sr) * K + sseg * 32;

    f32x4 acc[4][4] = {};
    uint4 ra[4], rb[4];
    const int NT = K >> 6;

    {
        const uint4* sa = (const uint4*)Ag;
        const uint4* sb = (const uint4*)Bg;
        ra[0]=sa[0]; ra[1]=sa[1]; ra[2]=sa[2]; ra[3]=sa[3];
        rb[0]=sb[0]; rb[1]=sb[1]; rb[2]=sb[2]; rb[3]=sb[3];
        uint4* dA = (uint4*)&sm[0][swb];
        uint4* dB = (uint4*)&sm[1][swb];
        dA[0]=ra[0]; dA[1]=ra[1]; dA[2]=ra[2]; dA[3]=ra[3];
        dB[0]=rb[0]; dB[1]=rb[1]; dB[2]=rb[2]; dB[3]=rb[3];
    }
    __syncthreads();

    for (int t = 0; t < NT; ++t) {
        if (t + 1 < NT) {
            const uint4* sa = (const uint4*)(Ag + (size_t)(t + 1) * 64);
            const uint4* sb = (const uint4*)(Bg + (size_t)(t + 1) * 64);
            ra[0]=sa[0]; ra[1]=sa[1]; ra[2]=sa[2]; ra[3]=sa[3];
            rb[0]=sb[0]; rb[1]=sb[1]; rb[2]=sb[2]; rb[3]=sb[3];
        }
        #pragma unroll
        for (int ks = 0; ks < 2; ++ks) {
            bf16x8 af[4], bfr[4];
            #pragma unroll
            for (int m = 0; m < 4; ++m)
                af[m] = *(const bf16x8*)&sm[0][(wr*64 + m*16 + lr) * ROWE + ks*32 + hi*8];
            #pragma unroll
            for (int n = 0; n < 4; ++n)
                bfr[n] = *(const bf16x8*)&sm[1][(wc*64 + n*16 + lr) * ROWE + ks*32 + hi*8];
            #pragma unroll
            for (int m = 0; m < 4; ++m)
                #pragma unroll
                for (int n = 0; n < 4; ++n)
                    acc[m][n] = __builtin_amdgcn_mfma_f32_16x16x32_bf16(
                        af[m], bfr[n], acc[m][n], 0, 0, 0);
        }
        __syncthreads();
        if (t + 1 < NT) {
            uint4* dA = (uint4*)&sm[0][swb];
            uint4* dB = (uint4*)&sm[1][swb];
            dA[0]=ra[0]; dA[1]=ra[1]; dA[2]=ra[2]; dA[3]=ra[3];
            dB[0]=rb[0]; dB[1]=rb[1]; dB[2]=rb[2]; dB[3]=rb[3];
            __syncthreads();
        }
    }

    #pragma unroll
    for (int m = 0; m < 4; ++m) {
        #pragma unroll
        for (int n = 0; n < 4; ++n) {
            const int r0 = row0 + wr*64 + m*16 + hi*4;
            const int c  = col0 + wc*64 + n*16 + lr;
            const float bv = bias ? bias[c] : 0.f;
            #pragma unroll
            for (int j = 0; j < 4; ++j) {
                const int r = r0 + j;
                float v = acc[m][n][j] + bv;
                if (EPI == 1) v = fmaxf(v, 0.f);
                if (EPI == 4) v = v - bf2f(X2[(size_t)r * N + c]);
                if (ACCUM)    v += C[(size_t)r * N + c];
                if (EPI == 7) {
                    if (c < 512) Ch [(size_t)r * 512 + c]       = f2bf(v);
                    else         Ch2[(size_t)r * 512 + (c-512)] = f2bf(gelu_f(v));
                } else {
                    if (C)  C [(size_t)r * N + c] = v;
                    if (Ch) Ch[(size_t)r * N + c] = f2bf(v);
                }
            }
        }
    }
}

// ---------------------------------------------------------------- dual-B GEMM
// T[M,N] = gelu(A@W1T^T) * (A@W2T^T)   -- 128(M) x 64(N) tile, both B's resident
__global__ __launch_bounds__(256, 2)
void dual_k(const ushort_t* __restrict__ A, const ushort_t* __restrict__ W1T,
            const ushort_t* __restrict__ W2T, ushort_t* __restrict__ Ch,
            int M, int N, int K)
{
    __shared__ ushort_t smA[128 * ROWE];
    __shared__ ushort_t smG[64 * ROWE];
    __shared__ ushort_t smV[64 * ROWE];

    int bx = blockIdx.x, by = blockIdx.y;
    swz_xy(bx, by);
    const int tid = threadIdx.x;
    const int l = tid & 63, w = tid >> 6;
    const int wr = w >> 1, wc = w & 1;
    const int lr = l & 15, hi = l >> 4;
    const int row0 = by * 128, col0 = bx * 64;

    const int sr = tid & 127, sseg = tid >> 7;
    const int swbA = sr * ROWE + sseg * 32;
    const int sr2 = tid & 63, kof2 = (tid >> 6) * 16;
    const int swbB = sr2 * ROWE + kof2;

    const ushort_t* Ag = A   + (size_t)(row0 + sr)  * K + sseg * 32;
    const ushort_t* Gg = W1T + (size_t)(col0 + sr2) * K + kof2;
    const ushort_t* Vg = W2T + (size_t)(col0 + sr2) * K + kof2;

    f32x4 ag[4][2] = {}, av[4][2] = {};
    uint4 ra[4], rg[2], rv[2];
    const int NT = K >> 6;

    {
        const uint4* sa = (const uint4*)Ag;
        const uint4* sg = (const uint4*)Gg;
        const uint4* sv = (const uint4*)Vg;
        ra[0]=sa[0]; ra[1]=sa[1]; ra[2]=sa[2]; ra[3]=sa[3];
        rg[0]=sg[0]; rg[1]=sg[1];
        rv[0]=sv[0]; rv[1]=sv[1];
        uint4* dA=(uint4*)&smA[swbA]; dA[0]=ra[0]; dA[1]=ra[1]; dA[2]=ra[2]; dA[3]=ra[3];
        uint4* dG=(uint4*)&smG[swbB]; dG[0]=rg[0]; dG[1]=rg[1];
        uint4* dV=(uint4*)&smV[swbB]; dV[0]=rv[0]; dV[1]=rv[1];
    }
    __syncthreads();

    for (int t = 0; t < NT; ++t) {
        if (t + 1 < NT) {
            const uint4* sa = (const uint4*)(Ag + (size_t)(t + 1) * 64);
            const uint4* sg = (const uint4*)(Gg + (size_t)(t + 1) * 64);
            const uint4* sv = (const uint4*)(Vg + (size_t)(t + 1) * 64);
            ra[0]=sa[0]; ra[1]=sa[1]; ra[2]=sa[2]; ra[3]=sa[3];
            rg[0]=sg[0]; rg[1]=sg[1];
            rv[0]=sv[0]; rv[1]=sv[1];
        }
        #pragma unroll
        for (int ks = 0; ks < 2; ++ks) {
            bf16x8 af[4], bg[2], bv[2];
            #pragma unroll
            for (int m = 0; m < 4; ++m)
                af[m] = *(const bf16x8*)&smA[(wr*64 + m*16 + lr) * ROWE + ks*32 + hi*8];
            #pragma unroll
            for (int n = 0; n < 2; ++n) {
                bg[n] = *(const bf16x8*)&smG[(wc*32 + n*16 + lr) * ROWE + ks*32 + hi*8];
                bv[n] = *(const bf16x8*)&smV[(wc*32 + n*16 + lr) * ROWE + ks*32 + hi*8];
            }
            #pragma unroll
            for (int m = 0; m < 4; ++m)
                #pragma unroll
                for (int n = 0; n < 2; ++n) {
                    ag[m][n] = __builtin_amdgcn_mfma_f32_16x16x32_bf16(af[m], bg[n], ag[m][n], 0, 0, 0);
                    av[m][n] = __builtin_amdgcn_mfma_f32_16x16x32_bf16(af[m], bv[n], av[m][n], 0, 0, 0);
                }
        }
        __syncthreads();
        if (t + 1 < NT) {
            uint4* dA=(uint4*)&smA[swbA]; dA[0]=ra[0]; dA[1]=ra[1]; dA[2]=ra[2]; dA[3]=ra[3];
            uint4* dG=(uint4*)&smG[swbB]; dG[0]=rg[0]; dG[1]=rg[1];
            uint4* dV=(uint4*)&smV[swbB]; dV[0]=rv[0]; dV[1]=rv[1];
            __syncthreads();
        }
    }

    #pragma unroll
    for (int m = 0; m < 4; ++m)
        #pragma unroll
        for (int n = 0; n < 2; ++n) {
            const int r0 = row0 + wr*64 + m*16 + hi*4;
            const int c  = col0 + wc*32 + n*16 + lr;
            #pragma unroll
            for (int j = 0; j < 4; ++j)
                Ch[(size_t)(r0 + j) * N + c] = f2bf(gelu_f(ag[m][n][j]) * av[m][n][j]);
        }
}

// ---------------------------------------------------------------- fused rgri+rec
// For each (b-block 128, dcol-block 64): loop t=0..5, GEMM r/i logits over K=512,
// sigmoid in-register, recurrence state h in acc slots, prod = h*gate -> bf16.
// Token rows are t-major: row = t*Bc + b.
__global__ __launch_bounds__(256, 2)
void rgri_rec_k(const ushort_t* __restrict__ u, const ushort_t* __restrict__ gate,
                const ushort_t* __restrict__ wrT, const ushort_t* __restrict__ wiT,
                const float* __restrict__ br, const float* __restrict__ bi,
                const float* __restrict__ a2, ushort_t* __restrict__ prod, int Bc)
{
    __shared__ ushort_t smA[128 * ROWE];
    __shared__ ushort_t smR[64 * ROWE];
    __shared__ ushort_t smI[64 * ROWE];

    int bx = blockIdx.x, by = blockIdx.y;
    swz_xy(bx, by);
    const int tid = threadIdx.x;
    const int l = tid & 63, w = tid >> 6;
    const int wr = w >> 1, wc = w & 1;
    const int lr = l & 15, hi = l >> 4;
    const int c0 = bx * 64, b0r = by * 128;

    const int sr = tid & 127, sseg = tid >> 7;
    const int swbA = sr * ROWE + sseg * 32;
    const int sr2 = tid & 63, kof2 = (tid >> 6) * 16;
    const int swbB = sr2 * ROWE + kof2;

    const ushort_t* Rg = wrT + (size_t)(c0 + sr2) * DRR + kof2;
    const ushort_t* Ig = wiT + (size_t)(c0 + sr2) * DRR + kof2;

    float a2v[2], brv[2], biv[2];
    #pragma unroll
    for (int n = 0; n < 2; ++n) {
        const int c = c0 + wc*32 + n*16 + lr;
        a2v[n] = a2[c]; brv[n] = br[c]; biv[n] = bi[c];
    }
    f32x4 h[4][2] = {};

    for (int t = 0; t < SS; ++t) {
        const ushort_t* Ag = u + (size_t)(t * Bc + b0r + sr) * DRR + sseg * 32;
        f32x4 ar[4][2] = {}, ai[4][2] = {};
        uint4 ra[4], rr_[2], ri_[2];
        {
            const uint4* sa = (const uint4*)Ag;
            const uint4* sg = (const uint4*)Rg;
            const uint4* sv = (const uint4*)Ig;
            ra[0]=sa[0]; ra[1]=sa[1]; ra[2]=sa[2]; ra[3]=sa[3];
            rr_[0]=sg[0]; rr_[1]=sg[1];
            ri_[0]=sv[0]; ri_[1]=sv[1];
            uint4* dA=(uint4*)&smA[swbA]; dA[0]=ra[0]; dA[1]=ra[1]; dA[2]=ra[2]; dA[3]=ra[3];
            uint4* dR=(uint4*)&smR[swbB]; dR[0]=rr_[0]; dR[1]=rr_[1];
            uint4* dI=(uint4*)&smI[swbB]; dI[0]=ri_[0]; dI[1]=ri_[1];
        }
        __syncthreads();
        const int NT = DRR >> 6;  // 8
        for (int kt = 0; kt < NT; ++kt) {
            if (kt + 1 < NT) {
                const uint4* sa = (const uint4*)(Ag + (kt + 1) * 64);
                const uint4* sg = (const uint4*)(Rg + (kt + 1) * 64);
                const uint4* sv = (const uint4*)(Ig + (kt + 1) * 64);
                ra[0]=sa[0]; ra[1]=sa[1]; ra[2]=sa[2]; ra[3]=sa[3];
                rr_[0]=sg[0]; rr_[1]=sg[1];
                ri_[0]=sv[0]; ri_[1]=sv[1];
            }
            #pragma unroll
            for (int ks = 0; ks < 2; ++ks) {
                bf16x8 af[4], bfr[2], bfi[2];
                #pragma unroll
                for (int m = 0; m < 4; ++m)
                    af[m] = *(const bf16x8*)&smA[(wr*64 + m*16 + lr) * ROWE + ks*32 + hi*8];
                #pragma unroll
                for (int n = 0; n < 2; ++n) {
                    bfr[n] = *(const bf16x8*)&smR[(wc*32 + n*16 + lr) * ROWE + ks*32 + hi*8];
                    bfi[n] = *(const bf16x8*)&smI[(wc*32 + n*16 + lr) * ROWE + ks*32 + hi*8];
                }
                #pragma unroll
                for (int m = 0; m < 4; ++m)
                    #pragma unroll
                    for (int n = 0; n < 2; ++n) {
                        ar[m][n] = __builtin_amdgcn_mfma_f32_16x16x32_bf16(af[m], bfr[n], ar[m][n], 0, 0, 0);
                        ai[m][n] = __builtin_amdgcn_mfma_f32_16x16x32_bf16(af[m], bfi[n], ai[m][n], 0, 0, 0);
                    }
            }
            __syncthreads();
            if (kt + 1 < NT) {
                uint4* dA=(uint4*)&smA[swbA]; dA[0]=ra[0]; dA[1]=ra[1]; dA[2]=ra[2]; dA[3]=ra[3];
                uint4* dR=(uint4*)&smR[swbB]; dR[0]=rr_[0]; dR[1]=rr_[1];
                uint4* dI=(uint4*)&smI[swbB]; dI[0]=ri_[0]; dI[1]=ri_[1];
                __syncthreads();
            }
        }
        // recurrence step for this t (r,i stay fp32 in-register)
        #pragma unroll
        for (int m = 0; m < 4; ++m) {
            #pragma unroll
            for (int n = 0; n < 2; ++n) {
                const int c = c0 + wc*32 + n*16 + lr;
                #pragma unroll
                for (int j = 0; j < 4; ++j) {
                    const int b = b0r + wr*64 + m*16 + hi*4 + j;
                    const size_t idx = (size_t)(t * Bc + b) * DRR + c;
                    const float rv = sigmoid_f(ar[m][n][j] + brv[n]);
                    const float iv = sigmoid_f(ai[m][n][j] + biv[n]);
                    const float e  = exp2f(a2v[n] * rv);
                    const float uu = bf2f(u[idx]);
                    const float hv = e * h[m][n][j]
                                   + sqrtf(fmaxf(0.f, 1.f - e * e)) * (iv * uu);
                    h[m][n][j] = hv;
                    prod[idx] = f2bf(hv * bf2f(gate[idx]));
                }
            }
        }
    }
}

// ---------------------------------------------------------------- small kernels

// transpose+convert weight: WT[n*K+k] = bf16(W[k*N+n])
__global__ void tr_k(const float* __restrict__ W, ushort_t* __restrict__ WT,
                     int K, int N)
{
    int idx = blockIdx.x * 256 + threadIdx.x;
    if (idx >= K * N) return;
    int n = idx / K, k = idx % K;
    WT[idx] = f2bf(W[(size_t)k * N + n]);
}

// bias_xy concat + a2 = -RG_C*softplus(lam)*log2(e)
__global__ void prep_k(const float* __restrict__ rg_bx, const float* __restrict__ rg_by,
                       const float* __restrict__ rg_lam,
                       float* __restrict__ bias_xy, float* __restrict__ a2)
{
    int i = blockIdx.x * 256 + threadIdx.x;
    if (i < 512) {
        bias_xy[i] = rg_bx[i];
        float lam = rg_lam[i];
        float sp = (lam > 20.f) ? lam : log1pf(expf(lam));
        a2[i] = -8.0f * sp * 1.4426950408889634f;
    } else if (i < 1024) {
        bias_xy[i] = rg_by[i - 512];
    }
}

// negm rows: rr = j*Bc + b; value = head[3+j,b0+b,:] + pred[...]
__global__ void negm_k(const float* __restrict__ head, const float* __restrict__ pred,
                       ushort_t* __restrict__ negm_h, int b0, int Bc)
{
    int idx = blockIdx.x * 256 + threadIdx.x;        // < Bc*2*384
    int d = idx % DD, rr = idx / DD;
    int j = (rr >= Bc) ? 1 : 0;
    int b = rr - j * Bc;
    size_t off = ((size_t)(KPP + j) * B_TOT + (b0 + b)) * DD + d;
    negm_h[idx] = f2bf(head[off] + pred[off]);
}

// grouped softmax attn + assemble x rows (t-major) + rmsnorm(g1) -> hbuf bf16
__global__ void asmrms_k(const float* __restrict__ init_f,
                         const float* __restrict__ head, const float* __restrict__ pred,
                         const float* __restrict__ w_ap, const float* __restrict__ b_ap,
                         const float* __restrict__ w_an, const float* __restrict__ b_an,
                         const ushort_t* __restrict__ nf, const float* __restrict__ g1,
                         float* __restrict__ x, ushort_t* __restrict__ hb,
                         int b0, int Bc)
{
    const int lb = blockIdx.x, gb = b0 + lb, lane = threadIdx.x;
    float hp[3][6], nv[2][6], iv[6], wap[6], wan[6];
    #pragma unroll
    for (int q = 0; q < 6; ++q) {
        int d = lane + 64 * q;
        wap[q] = w_ap[d]; wan[q] = w_an[d];
        iv[q] = init_f[(size_t)gb * DD + d];
    }
    float lp[3], ln2[2];
    #pragma unroll
    for (int j = 0; j < 3; ++j) {
        float p = 0.f;
        #pragma unroll
        for (int q = 0; q < 6; ++q) {
            int d = lane + 64 * q;
            size_t off = ((size_t)j * B_TOT + gb) * DD + d;
            float v = head[off] + pred[off];
            hp[j][q] = v;
            p += v * wap[q];
        }
        lp[j] = wave_red_sum(p) + b_ap[0];
    }
    #pragma unroll
    for (int j = 0; j < 2; ++j) {
        float p = 0.f;
        #pragma unroll
        for (int q = 0; q < 6; ++q) {
            int d = lane + 64 * q;
            float v = bf2f(nf[((size_t)j * Bc + lb) * DD + d]);
            nv[j][q] = v;
            p += v * wan[q];
        }
        ln2[j] = wave_red_sum(p) + b_an[0];
    }
    float mp = fmaxf(lp[0], fmaxf(lp[1], lp[2]));
    float e0 = expf(lp[0]-mp), e1 = expf(lp[1]-mp), e2 = expf(lp[2]-mp);
    float sp = e0 + e1 + e2;
    float awp[3] = {e0/sp, e1/sp, e2/sp};
    float mn = fmaxf(ln2[0], ln2[1]);
    float f0 = expf(ln2[0]-mn), f1 = expf(ln2[1]-mn);
    float sn = f0 + f1;
    float awn[2] = {f0/sn, f1/sn};

    // rows t-major: row = t*Bc + lb
    #pragma unroll
    for (int t = 0; t < SS; ++t) {
        float rowv[6], ss = 0.f;
        #pragma unroll
        for (int q = 0; q < 6; ++q) {
            float v;
            if (t == 0)      v = iv[q];
            else if (t <= 3) v = hp[t-1][q] * awp[t-1];
            else             v = nv[t-4][q] * awn[t-4];
            rowv[q] = v;
            ss += v * v;
        }
        ss = wave_red_sum(ss);
        float sc = rsqrtf(ss / (float)DD + 1e-6f);
        float* xr = x + (size_t)(t * Bc + lb) * DD;
        ushort_t* hr = hb + (size_t)(t * Bc + lb) * DD;
        #pragma unroll
        for (int q = 0; q < 6; ++q) {
            int d = lane + 64 * q;
            xr[d] = rowv[q];
            hr[d] = f2bf(rowv[q] * g1[d] * sc);
        }
    }
}

// rmsnorm per row -> bf16; one wave per row, 4 rows per block
__global__ void rms_k(const float* __restrict__ x, const float* __restrict__ g,
                      ushort_t* __restrict__ h)
{
    int row  = blockIdx.x * 4 + (threadIdx.x >> 6);
    int lane = threadIdx.x & 63;
    const float* xr = x + (size_t)row * DD;
    float ss = 0.f;
    for (int d = lane; d < DD; d += 64) { float v = xr[d]; ss += v * v; }
    ss = wave_red_sum(ss);
    float sc = rsqrtf(ss / (float)DD + 1e-6f);
    ushort_t* hr = h + (size_t)row * DD;
    for (int d = lane; d < DD; d += 64) hr[d] = f2bf(xr[d] * g[d] * sc);
}

// wproj[d] = sum_k fa_wo[d,k] * fa_wl[k]
__global__ void wproj_k(const float* __restrict__ fa_wo, const float* __restrict__ fa_wl,
                        float* __restrict__ wproj)
{
    int d = threadIdx.x;  // 384 threads
    float s = 0.f;
    for (int k = 0; k < DD; ++k) s += fa_wo[(size_t)d * DD + k] * fa_wl[k];
    wproj[d] = s;
}

// logits = Afa(bf16) @ wproj (+bl), softmax over S, out = (1/6) sum_t x_t * w_t
__global__ void final_k(const float* __restrict__ x, const ushort_t* __restrict__ Afa,
                        const float* __restrict__ wproj, const float* __restrict__ fa_bl,
                        float* __restrict__ out, int b0, int Bc)
{
    const int lb = blockIdx.x, gb = b0 + lb, lane = threadIdx.x;
    float lg[SS];
    #pragma unroll
    for (int t = 0; t < SS; ++t) {
        float p = 0.f;
        const ushort_t* ar = Afa + (size_t)(t * Bc + lb) * DD;
        #pragma unroll
        for (int q = 0; q < 6; ++q) {
            int d = lane + 64 * q;
            p += bf2f(ar[d]) * wproj[d];
        }
        lg[t] = wave_red_sum(p) + fa_bl[0];
    }
    float m = lg[0];
    #pragma unroll
    for (int t = 1; t < SS; ++t) m = fmaxf(m, lg[t]);
    float e[SS], s = 0.f;
    #pragma unroll
    for (int t = 0; t < SS; ++t) { e[t] = expf(lg[t] - m); s += e[t]; }
    float inv = 1.0f / s;
    #pragma unroll
    for (int q = 0; q < 6; ++q) {
        int d = lane + 64 * q;
        float acc = 0.f;
        #pragma unroll
        for (int t = 0; t < SS; ++t)
            acc += x[(size_t)(t * Bc + lb) * DD + d] * (e[t] * inv);
        out[(size_t)gb * DD + d] = acc * (1.0f / 6.0f);
    }
}

// ---------------------------------------------------------------- launch
extern "C" void kernel_launch(void* const* d_in, const int* in_sizes, int n_in,
                              void* d_out, int out_size, void* d_ws, size_t ws_size,
                              hipStream_t stream)
{
    (void)in_sizes; (void)n_in; (void)out_size;
    const float* init_f  = (const float*)d_in[0];
    const float* head    = (const float*)d_in[1];
    const float* pred    = (const float*)d_in[2];
    const float* w_ap    = (const float*)d_in[3];
    const float* b_ap    = (const float*)d_in[4];
    const float* w_an    = (const float*)d_in[5];
    const float* b_an    = (const float*)d_in[6];
    const float* nt_w1   = (const float*)d_in[7];
    const float* nt_b1   = (const float*)d_in[8];
    const float* nt_w2   = (const float*)d_in[9];
    const float* nt_b2   = (const float*)d_in[10];
    const float* g1      = (const float*)d_in[11];
    const float* rg_wx   = (const float*)d_in[12];
    const float* rg_bx   = (const float*)d_in[13];
    const float* rg_wy   = (const float*)d_in[14];
    const float* rg_by   = (const float*)d_in[15];
    const float* rg_wr   = (const float*)d_in[16];
    const float* rg_br   = (const float*)d_in[17];
    const float* rg_wi   = (const float*)d_in[18];
    const float* rg_bi   = (const float*)d_in[19];
    const float* rg_lam  = (const float*)d_in[20];
    const float* rg_wo   = (const float*)d_in[21];
    const float* rg_bo   = (const float*)d_in[22];
    const float* g2      = (const float*)d_in[23];
    const float* mlp_wg  = (const float*)d_in[24];
    const float* mlp_wv  = (const float*)d_in[25];
    const float* mlp_wo  = (const float*)d_in[26];
    const float* fa_wg   = (const float*)d_in[27];
    const float* fa_wv   = (const float*)d_in[28];
    const float* fa_wo   = (const float*)d_in[29];
    const float* fa_wl   = (const float*)d_in[30];
    const float* fa_bl   = (const float*)d_in[31];
    float* out = (float*)d_out;

    float* ws_f    = (float*)d_ws;
    float* wproj   = ws_f;                 // 512 f32 slot
    float* bias_xy = ws_f + 512;           // 1024
    float* a2      = ws_f + 1536;          // 512
    ushort_t* wt   = (ushort_t*)(ws_f + 2048);

    // bf16 transposed weights (offsets in bf16 elems)
    ushort_t* ntw1T = wt + 0;
    ushort_t* ntw2T = wt + 393216;
    ushort_t* wxyT  = wt + 786432;
    ushort_t* wrT   = wt + 1179648;
    ushort_t* wiT   = wt + 1441792;
    ushort_t* woT   = wt + 1703936;
    ushort_t* mwgT  = wt + 1900544;
    ushort_t* mwvT  = wt + 2342912;
    ushort_t* mwoT  = wt + 2785280;
    ushort_t* fwgT  = wt + 3227648;
    ushort_t* fwvT  = wt + 3375104;       // end 3522560 bf16 = 1761280 f32

    struct WSpec { const float* W; ushort_t* WT; int K, N; };
    const WSpec specs[12] = {
        {nt_w1, ntw1T, DD, HH}, {nt_w2, ntw2T, HH, DD},
        {rg_wx, wxyT, DD, DRR}, {rg_wy, wxyT + 512*384, DD, DRR},
        {rg_wr, wrT, DRR, DRR}, {rg_wi, wiT, DRR, DRR}, {rg_wo, woT, DRR, DD},
        {mlp_wg, mwgT, DD, DMM}, {mlp_wv, mwvT, DD, DMM}, {mlp_wo, mwoT, DMM, DD},
        {fa_wg, fwgT, DD, DD}, {fa_wv, fwvT, DD, DD},
    };
    for (int i = 0; i < 12; ++i) {
        int e = specs[i].K * specs[i].N;
        tr_k<<<(e + 255) / 256, 256, 0, stream>>>(specs[i].W, specs[i].WT,
                                                  specs[i].K, specs[i].N);
    }
    prep_k<<<4, 256, 0, stream>>>(rg_bx, rg_by, rg_lam, bias_xy, a2);
    wproj_k<<<1, DD, 0, stream>>>(fa_wo, fa_wl, wproj);

    const size_t fixed_f32 = 2048 + 1761280;
    const size_t per_b_f32 = 16768;
    int Bc = B_TOT;
    while (Bc > 128 && (fixed_f32 + per_b_f32 * (size_t)Bc) * 4 > ws_size) Bc >>= 1;

    float* arena = ws_f + fixed_f32;

    for (int b0 = 0; b0 < B_TOT; b0 += Bc) {
        const int M  = Bc * SS;
        const int M2 = Bc * KNN;
        float*    xbuf = arena;                                  // 2304*Bc f32
        ushort_t* xh   = (ushort_t*)(arena + (size_t)2304  * Bc); // M*384 bf16
        ushort_t* hb   = (ushort_t*)(arena + (size_t)3456  * Bc); // M*384 bf16
        ushort_t* negm = (ushort_t*)(arena + (size_t)4608  * Bc); // M2*384 bf16
        ushort_t* hid  = (ushort_t*)(arena + (size_t)4992  * Bc); // M2*1024 bf16
        ushort_t* nf   = (ushort_t*)(arena + (size_t)6016  * Bc); // M2*384 bf16
        ushort_t* uh   = (ushort_t*)(arena + (size_t)6400  * Bc); // M*512 bf16
        ushort_t* gth  = (ushort_t*)(arena + (size_t)7936  * Bc); // M*512 bf16
        ushort_t* pr   = (ushort_t*)(arena + (size_t)9472  * Bc); // M*512 bf16
        ushort_t* h2   = (ushort_t*)(arena + (size_t)11008 * Bc); // M*384 bf16
        ushort_t* Th   = (ushort_t*)(arena + (size_t)12160 * Bc); // M*1152 bf16
        ushort_t* Afa  = (ushort_t*)(arena + (size_t)15616 * Bc); // M*384 bf16

        // stage 1: neg messages + MLP residual + attention assembly (+rms g1)
        negm_k<<<Bc * 3, 256, 0, stream>>>(head, pred, negm, b0, Bc);
        bgemm<1, false><<<dim3(HH/128, M2/128), 256, 0, stream>>>(
            negm, ntw1T, nt_b1, nullptr, nullptr, hid, nullptr, M2, HH, DD);
        bgemm<4, false><<<dim3(DD/128, M2/128), 256, 0, stream>>>(
            hid, ntw2T, nt_b2, negm, nullptr, nf, nullptr, M2, DD, HH);
        asmrms_k<<<Bc, 64, 0, stream>>>(init_f, head, pred, w_ap, b_ap, w_an, b_an,
                                        nf, g1, xbuf, hb, b0, Bc);

        // Griffin recurrent branch
        bgemm<7, false><<<dim3(1024/128, M/128), 256, 0, stream>>>(
            hb, wxyT, bias_xy, nullptr, nullptr, uh, gth, M, 1024, DD);
        rgri_rec_k<<<dim3(DRR/64, Bc/128), 256, 0, stream>>>(
            uh, gth, wrT, wiT, rg_br, rg_bi, a2, pr, Bc);
        bgemm<0, true><<<dim3(DD/128, M/128), 256, 0, stream>>>(
            pr, woT, rg_bo, nullptr, xbuf, nullptr, nullptr, M, DD, DRR);

        // gated-MLP residual branch
        rms_k<<<M / 4, 256, 0, stream>>>(xbuf, g2, h2);
        dual_k<<<dim3(DMM/64, M/128), 256, 0, stream>>>(h2, mwgT, mwvT, Th, M, DMM, DD);
        bgemm<0, true><<<dim3(DD/128, M/128), 256, 0, stream>>>(
            Th, mwoT, nullptr, nullptr, xbuf, xh, nullptr, M, DD, DMM);

        // final attention aggregation
        dual_k<<<dim3(DD/64, M/128), 256, 0, stream>>>(xh, fwgT, fwvT, Afa, M, DD, DD);
        final_k<<<Bc, 64, 0, stream>>>(xbuf, Afa, wproj, fa_bl, out, b0, Bc);
    }
}